// Round 17
// baseline (246.709 us; speedup 1.0000x reference)
//
#include <hip/hip_runtime.h>
#include <cstdint>

#define BB 4
#define SS 2048
#define DD 1024
#define HH 16
#define HDIM 64
#define MTOT (BB*SS)

using half_t = _Float16;
typedef _Float16 half2v __attribute__((ext_vector_type(2)));
typedef _Float16 half4v __attribute__((ext_vector_type(4)));
typedef _Float16 half8v __attribute__((ext_vector_type(8)));
typedef float f32x4 __attribute__((ext_vector_type(4)));

#if defined(__has_builtin)
#if __has_builtin(__builtin_amdgcn_exp2f)
#define ATTN_EXP2(x) __builtin_amdgcn_exp2f(x)
#endif
#if __has_builtin(__builtin_amdgcn_cvt_pkrtz)
#define ATTN_PKRTZ 1
#endif
#endif

// async global->LDS, 16B per lane; LDS dest = wave-uniform base + lane*16
__device__ __forceinline__ void glds16(const half_t* g, half_t* l) {
    __builtin_amdgcn_global_load_lds(g, l, 16, 0, 0);
}

// ---------------- fp32 -> (hi,lo) f16 split (fallback path) ----------------
__global__ __launch_bounds__(256) void split_hi_lo(const float* __restrict__ x,
    half_t* __restrict__ hi, half_t* __restrict__ lo, int n4)
{
    const int i = blockIdx.x * blockDim.x + threadIdx.x;
    if (i >= n4) return;
    float4 v = reinterpret_cast<const float4*>(x)[i];
    float vv[4] = {v.x, v.y, v.z, v.w};
    half4v h, l;
    #pragma unroll
    for (int j = 0; j < 4; ++j) {
        half_t hh = (half_t)vv[j];
        h[j] = hh;
        l[j] = (half_t)(vv[j] - (float)hh);
    }
    reinterpret_cast<half4v*>(hi)[i] = h;
    reinterpret_cast<half4v*>(lo)[i] = l;
}

// ---------------- cast 4 weight matrices to f16 (hi only) in one launch ----------------
__global__ __launch_bounds__(256) void cast_w4(
    const float* __restrict__ w0, const float* __restrict__ w1,
    const float* __restrict__ w2, const float* __restrict__ w3,
    half_t* __restrict__ hi)
{
    const int z = blockIdx.z;
    const float* src = z == 0 ? w0 : z == 1 ? w1 : z == 2 ? w2 : w3;
    const size_t base4 = (size_t)z * (DD * DD / 4);
    const size_t i = base4 + blockIdx.x * 256 + threadIdx.x;
    float4 v = reinterpret_cast<const float4*>(src)[blockIdx.x * 256 + threadIdx.x];
    float vv[4] = {v.x, v.y, v.z, v.w};
    half4v h;
    #pragma unroll
    for (int j = 0; j < 4; ++j) h[j] = (half_t)vv[j];
    reinterpret_cast<half4v*>(hi)[i] = h;
}

// ---------------- cast 3 activation tensors to f16 (per-z dst) ----------------
__global__ __launch_bounds__(256) void cast_a3(
    const float* __restrict__ a0, const float* __restrict__ a1,
    const float* __restrict__ a2,
    half_t* __restrict__ d0, half_t* __restrict__ d1, half_t* __restrict__ d2)
{
    const int z = blockIdx.z;
    const float* src = z == 0 ? a0 : z == 1 ? a1 : a2;
    half_t*      dst = z == 0 ? d0 : z == 1 ? d1 : d2;
    const size_t i = (size_t)blockIdx.x * 256 + threadIdx.x;
    float4 v = reinterpret_cast<const float4*>(src)[i];
    float vv[4] = {v.x, v.y, v.z, v.w};
    half4v h;
    #pragma unroll
    for (int j = 0; j < 4; ++j) h[j] = (half_t)vv[j];
    reinterpret_cast<half4v*>(dst)[i] = h;
}

// ---------------- projection GEMM (out-style): C[z] = f16(a16[z] @ f16(W[z])^T + b[z]) ----------------
// Pure gload_lds both operands (A pre-cast to f16 by cast_a3 — identical RTE
// numerics to the old in-kernel cast). Structure == proven gemm_out.
__global__ __launch_bounds__(256, 5) void gemm_projf(
    const half_t* __restrict__ A0, const half_t* __restrict__ A1,
    const half_t* __restrict__ A2,
    const half_t* __restrict__ WH,
    const float* __restrict__ B0, const float* __restrict__ B1,
    const float* __restrict__ B2,
    half_t* __restrict__ C0, half_t* __restrict__ C1, half_t* __restrict__ C2)
{
    __shared__ __align__(16) half_t AhS[2][128 * 32];
    __shared__ __align__(16) half_t WhS[2][128 * 32];

    const int z = blockIdx.z;
    const half_t* A    = z == 0 ? A0 : z == 1 ? A1 : A2;
    const float*  bias = z == 0 ? B0 : z == 1 ? B1 : B2;
    half_t*       C    = z == 0 ? C0 : z == 1 ? C1 : C2;
    const half_t* WHz  = WH + (size_t)z * (DD * DD);

    const int tid = threadIdx.x;
    const int l = tid & 63, w = tid >> 6;
    const int lr = l & 15, lg = l >> 4;
    const int wr = w >> 1, wc = w & 1;
    const int m0 = blockIdx.x * 128, n0 = blockIdx.y * 128;
    const int wlrow = l >> 2, wlcol = (l & 3) * 8;

    f32x4 acc[4][4] = {};

    // prologue: stage tile 0
    #pragma unroll
    for (int i = 0; i < 2; ++i) {
        const int rr = (w * 2 + i) * 16 + wlrow;
        glds16(A   + (size_t)(m0 + rr) * DD + wlcol, &AhS[0][(w * 2 + i) * 512]);
        glds16(WHz + (size_t)(n0 + rr) * DD + wlcol, &WhS[0][(w * 2 + i) * 512]);
    }
    __syncthreads();

    for (int t = 0; t < 32; ++t) {
        const int cur = t & 1, nxt = cur ^ 1;
        if (t < 31) {
            const int kk1 = (t + 1) * 32;
            #pragma unroll
            for (int i = 0; i < 2; ++i) {
                const int rr = (w * 2 + i) * 16 + wlrow;
                glds16(A   + (size_t)(m0 + rr) * DD + kk1 + wlcol, &AhS[nxt][(w * 2 + i) * 512]);
                glds16(WHz + (size_t)(n0 + rr) * DD + kk1 + wlcol, &WhS[nxt][(w * 2 + i) * 512]);
            }
        }

        half8v af[4];
        #pragma unroll
        for (int mt = 0; mt < 4; ++mt)
            af[mt] = *reinterpret_cast<const half8v*>(&AhS[cur][(wr * 64 + mt * 16 + lr) * 32 + 8 * lg]);
        #pragma unroll
        for (int nt = 0; nt < 4; ++nt) {
            half8v wf = *reinterpret_cast<const half8v*>(&WhS[cur][(wc * 64 + nt * 16 + lr) * 32 + 8 * lg]);
            #pragma unroll
            for (int mt = 0; mt < 4; ++mt)
                acc[mt][nt] = __builtin_amdgcn_mfma_f32_16x16x32_f16(af[mt], wf, acc[mt][nt], 0, 0, 0);
        }
        __syncthreads();
    }

    #pragma unroll
    for (int nt = 0; nt < 4; ++nt) {
        const int n = n0 + wc * 64 + nt * 16 + lr;
        const float bn = bias[n];
        #pragma unroll
        for (int mt = 0; mt < 4; ++mt) {
            const int mbase = m0 + wr * 64 + mt * 16 + 4 * lg;
            #pragma unroll
            for (int j = 0; j < 4; ++j)
                C[(size_t)(mbase + j) * DD + n] = (half_t)(acc[mt][nt][j] + bn);
        }
    }
}

// ---------------- output GEMM: out = x16 @ f16(Wo)^T + bo ----------------
__global__ __launch_bounds__(256, 5) void gemm_out(
    const half_t* __restrict__ Ag,
    const half_t* __restrict__ WHz,
    const float* __restrict__ bias, float* __restrict__ C)
{
    __shared__ __align__(16) half_t AhS[2][128 * 32];
    __shared__ __align__(16) half_t WhS[2][128 * 32];

    const int tid = threadIdx.x;
    const int l = tid & 63, w = tid >> 6;
    const int lr = l & 15, lg = l >> 4;
    const int wr = w >> 1, wc = w & 1;
    const int m0 = blockIdx.x * 128, n0 = blockIdx.y * 128;
    const int wlrow = l >> 2, wlcol = (l & 3) * 8;

    f32x4 acc[4][4] = {};

    // prologue: stage tile 0
    #pragma unroll
    for (int i = 0; i < 2; ++i) {
        const int rr = (w * 2 + i) * 16 + wlrow;
        glds16(Ag  + (size_t)(m0 + rr) * DD + wlcol, &AhS[0][(w * 2 + i) * 512]);
        glds16(WHz + (size_t)(n0 + rr) * DD + wlcol, &WhS[0][(w * 2 + i) * 512]);
    }
    __syncthreads();

    for (int t = 0; t < 32; ++t) {
        const int cur = t & 1, nxt = cur ^ 1;
        if (t < 31) {
            const int kk1 = (t + 1) * 32;
            #pragma unroll
            for (int i = 0; i < 2; ++i) {
                const int rr = (w * 2 + i) * 16 + wlrow;
                glds16(Ag  + (size_t)(m0 + rr) * DD + kk1 + wlcol, &AhS[nxt][(w * 2 + i) * 512]);
                glds16(WHz + (size_t)(n0 + rr) * DD + kk1 + wlcol, &WhS[nxt][(w * 2 + i) * 512]);
            }
        }

        half8v af[4];
        #pragma unroll
        for (int mt = 0; mt < 4; ++mt)
            af[mt] = *reinterpret_cast<const half8v*>(&AhS[cur][(wr * 64 + mt * 16 + lr) * 32 + 8 * lg]);
        #pragma unroll
        for (int nt = 0; nt < 4; ++nt) {
            half8v wf = *reinterpret_cast<const half8v*>(&WhS[cur][(wc * 64 + nt * 16 + lr) * 32 + 8 * lg]);
            #pragma unroll
            for (int mt = 0; mt < 4; ++mt)
                acc[mt][nt] = __builtin_amdgcn_mfma_f32_16x16x32_f16(af[mt], wf, acc[mt][nt], 0, 0, 0);
        }
        __syncthreads();
    }

    #pragma unroll
    for (int nt = 0; nt < 4; ++nt) {
        const int n = n0 + wc * 64 + nt * 16 + lr;
        const float bn = bias[n];
        #pragma unroll
        for (int mt = 0; mt < 4; ++mt) {
            const int mbase = m0 + wr * 64 + mt * 16 + 4 * lg;
            #pragma unroll
            for (int j = 0; j < 4; ++j)
                C[(size_t)(mbase + j) * DD + n] = acc[mt][nt][j] + bn;
        }
    }
}

// ---------------- old split GEMM (fallback path only) ----------------
template<int MODE, typename TC>
__global__ __launch_bounds__(256) void gemm3s(
    const half_t* __restrict__ Ah, const half_t* __restrict__ Al,
    const float* __restrict__ Af,
    const half_t* __restrict__ Wh, const half_t* __restrict__ Wl,
    const float* __restrict__ bias, TC* __restrict__ C,
    int Kdim, int Ndim)
{
    constexpr int LDT = 72;
    __shared__ __align__(16) half_t As[128 * LDT];
    __shared__ __align__(16) half_t Ws[128 * LDT];
    const int tid = threadIdx.x;
    const int l = tid & 63, w = tid >> 6;
    const int lr = l & 15, lg = l >> 4;
    const int wr = w >> 1, wc = w & 1;
    const int m0 = blockIdx.y * 128, n0 = blockIdx.x * 128;
    const int r = tid >> 1, t = tid & 1;

    f32x4 acc[4][4] = {};

    for (int kk = 0; kk < Kdim; kk += 32) {
        __syncthreads();
        if constexpr (MODE == 1) {
            const float* ap = Af + (size_t)(m0 + r) * Kdim + kk + 16 * t;
            half_t hbuf[16], lbuf[16];
            #pragma unroll
            for (int u = 0; u < 4; ++u) {
                float4 v = *reinterpret_cast<const float4*>(ap + 4 * u);
                float vv[4] = {v.x, v.y, v.z, v.w};
                #pragma unroll
                for (int j = 0; j < 4; ++j) {
                    half_t hh = (half_t)vv[j];
                    hbuf[4 * u + j] = hh;
                    lbuf[4 * u + j] = (half_t)(vv[j] - (float)hh);
                }
            }
            *reinterpret_cast<int4*>(&As[r * LDT + 16 * t])          = *reinterpret_cast<int4*>(hbuf);
            *reinterpret_cast<int4*>(&As[r * LDT + 16 * t + 8])      = *reinterpret_cast<int4*>(hbuf + 8);
            *reinterpret_cast<int4*>(&As[r * LDT + 40 + 16 * t])     = *reinterpret_cast<int4*>(lbuf);
            *reinterpret_cast<int4*>(&As[r * LDT + 40 + 16 * t + 8]) = *reinterpret_cast<int4*>(lbuf + 8);
        } else {
            const half_t* ap = Ah + (size_t)(m0 + r) * Kdim + kk + 16 * t;
            *reinterpret_cast<int4*>(&As[r * LDT + 16 * t])     = *reinterpret_cast<const int4*>(ap);
            *reinterpret_cast<int4*>(&As[r * LDT + 16 * t + 8]) = *reinterpret_cast<const int4*>(ap + 8);
        }
        {
            const half_t* wp = Wh + (size_t)(n0 + r) * Kdim + kk + 16 * t;
            *reinterpret_cast<int4*>(&Ws[r * LDT + 16 * t])     = *reinterpret_cast<const int4*>(wp);
            *reinterpret_cast<int4*>(&Ws[r * LDT + 16 * t + 8]) = *reinterpret_cast<const int4*>(wp + 8);
            const half_t* wlp = Wl + (size_t)(n0 + r) * Kdim + kk + 16 * t;
            *reinterpret_cast<int4*>(&Ws[r * LDT + 40 + 16 * t])     = *reinterpret_cast<const int4*>(wlp);
            *reinterpret_cast<int4*>(&Ws[r * LDT + 40 + 16 * t + 8]) = *reinterpret_cast<const int4*>(wlp + 8);
        }
        __syncthreads();

        half8v af[4], alf[4];
        #pragma unroll
        for (int mt = 0; mt < 4; ++mt) {
            af[mt] = *reinterpret_cast<const half8v*>(&As[(wr * 64 + mt * 16 + lr) * LDT + 8 * lg]);
            if constexpr (MODE != 2)
                alf[mt] = *reinterpret_cast<const half8v*>(&As[(wr * 64 + mt * 16 + lr) * LDT + 40 + 8 * lg]);
        }
        #pragma unroll
        for (int nt = 0; nt < 4; ++nt) {
            half8v wf  = *reinterpret_cast<const half8v*>(&Ws[(wc * 64 + nt * 16 + lr) * LDT + 8 * lg]);
            half8v wlf = *reinterpret_cast<const half8v*>(&Ws[(wc * 64 + nt * 16 + lr) * LDT + 40 + 8 * lg]);
            #pragma unroll
            for (int mt = 0; mt < 4; ++mt) {
                acc[mt][nt] = __builtin_amdgcn_mfma_f32_16x16x32_f16(af[mt], wf, acc[mt][nt], 0, 0, 0);
                acc[mt][nt] = __builtin_amdgcn_mfma_f32_16x16x32_f16(af[mt], wlf, acc[mt][nt], 0, 0, 0);
                if constexpr (MODE != 2)
                    acc[mt][nt] = __builtin_amdgcn_mfma_f32_16x16x32_f16(alf[mt], wf, acc[mt][nt], 0, 0, 0);
            }
        }
    }

    #pragma unroll
    for (int nt = 0; nt < 4; ++nt) {
        const int n = n0 + wc * 64 + nt * 16 + lr;
        const float bn = bias[n];
        #pragma unroll
        for (int mt = 0; mt < 4; ++mt) {
            const int mbase = m0 + wr * 64 + mt * 16 + 4 * lg;
            #pragma unroll
            for (int j = 0; j < 4; ++j) {
                float v = acc[mt][nt][j] + bn;
                if constexpr (sizeof(TC) == 4)
                    C[(size_t)(mbase + j) * Ndim + n] = v;
                else
                    C[(size_t)(mbase + j) * Ndim + n] = (half_t)v;
            }
        }
    }
}

// ---------------- fp32 vector GEMM (ultimate fallback only) ----------------
template<typename TA, typename TC>
__global__ __launch_bounds__(256) void gemm_bias(const TA* __restrict__ A,
    const float* __restrict__ W, const float* __restrict__ bias,
    TC* __restrict__ C, int Mdim, int Ndim, int Kdim)
{
    constexpr int BK = 16;
    __shared__ float As[BK][68];
    __shared__ float Ws[BK][68];
    const int tx = threadIdx.x, ty = threadIdx.y;
    const int tid = ty * 16 + tx;
    const int m0 = blockIdx.y * 64, n0 = blockIdx.x * 64;
    const int lrow = tid >> 2;
    const int lc4  = (tid & 3) * 4;

    float acc[4][4] = {};
    for (int kk = 0; kk < Kdim; kk += BK) {
        {
            const TA* ap = A + (size_t)(m0 + lrow) * Kdim + kk + lc4;
            float a0, a1, a2, a3;
            if constexpr (sizeof(TA) == 4) {
                float4 v = *reinterpret_cast<const float4*>(ap);
                a0 = v.x; a1 = v.y; a2 = v.z; a3 = v.w;
            } else {
                half2v v0 = *reinterpret_cast<const half2v*>(ap);
                half2v v1 = *reinterpret_cast<const half2v*>(ap + 2);
                a0 = (float)v0[0]; a1 = (float)v0[1];
                a2 = (float)v1[0]; a3 = (float)v1[1];
            }
            As[lc4 + 0][lrow] = a0; As[lc4 + 1][lrow] = a1;
            As[lc4 + 2][lrow] = a2; As[lc4 + 3][lrow] = a3;
            const float* wp = W + (size_t)(n0 + lrow) * Kdim + kk + lc4;
            float4 wv = *reinterpret_cast<const float4*>(wp);
            Ws[lc4 + 0][lrow] = wv.x; Ws[lc4 + 1][lrow] = wv.y;
            Ws[lc4 + 2][lrow] = wv.z; Ws[lc4 + 3][lrow] = wv.w;
        }
        __syncthreads();
        #pragma unroll
        for (int k = 0; k < BK; ++k) {
            float4 av = *reinterpret_cast<const float4*>(&As[k][ty * 4]);
            float4 bv = *reinterpret_cast<const float4*>(&Ws[k][tx * 4]);
            float a[4] = {av.x, av.y, av.z, av.w};
            float b[4] = {bv.x, bv.y, bv.z, bv.w};
            #pragma unroll
            for (int i = 0; i < 4; ++i)
                #pragma unroll
                for (int j = 0; j < 4; ++j)
                    acc[i][j] = fmaf(a[i], b[j], acc[i][j]);
        }
        __syncthreads();
    }
    #pragma unroll
    for (int i = 0; i < 4; ++i) {
        const int m = m0 + ty * 4 + i;
        #pragma unroll
        for (int j = 0; j < 4; ++j) {
            const int n = n0 + tx * 4 + j;
            float v = acc[i][j] + bias[n];
            if constexpr (sizeof(TC) == 4)
                C[(size_t)m * Ndim + n] = v;
            else
                C[(size_t)m * Ndim + n] = (half_t)v;
        }
    }
}

// ---------------- single-pass fused attention (unchanged from round 16) ----------------
__global__ __launch_bounds__(256, 4) void attn_fused(const half_t* __restrict__ Q,
    const half_t* __restrict__ K, const half_t* __restrict__ V,
    half_t* __restrict__ X)
{
    __shared__ __align__(16) half_t KsL[2][64 * 64];   // linear, swizzled+permuted content
    __shared__ __align__(16) half_t Vt[2][64 * 72];    // transposed V

    const int tid = threadIdx.x;
    const int l   = tid & 63;
    const int w   = tid >> 6;
    const int lr  = l & 15;
    const int lg  = l >> 4;

    const int phys = blockIdx.x;
    const int virt = (phys & 7) * 128 + (phys >> 3);
    const int qb = virt & 15;
    const int h  = (virt >> 4) & 15;
    const int b  = virt >> 8;

    const int q0 = qb * 128 + w * 32;
    const size_t hoff = (size_t)(b * SS) * DD + h * HDIM;

    // Q fragments, pre-scaled by 1/8
    half8v qf[2][2];
    #pragma unroll
    for (int s = 0; s < 2; ++s) {
        const half_t* qp = Q + hoff + (size_t)(q0 + s * 16 + lr) * DD;
        #pragma unroll
        for (int hb = 0; hb < 2; ++hb) {
            half8v v = *reinterpret_cast<const half8v*>(qp + hb * 32 + 8 * lg);
            #pragma unroll
            for (int e = 0; e < 8; ++e) v[e] *= (half_t)0.125f;
            qf[s][hb] = v;
        }
    }

    // K staging: per-lane global source offsets with row-permutation pi and
    // XOR chunk swizzle keyed on LDS row R (both-sides rule, m173 pattern)
    int koffH[2];
    #pragma unroll
    for (int i = 0; i < 2; ++i) {
        const int R    = (w * 2 + i) * 8 + (l >> 3);   // LDS row this lane fills
        const int gkey = ((R >> 5) & 1) * 32 + ((R >> 2) & 3) * 8
                       + ((R >> 4) & 1) * 4 + (R & 3); // pi(R)
        const int gc   = (l & 7) ^ (R & 7);
        koffH[i] = gkey * DD + gc * 8;
    }
    // swizzled frag-read indices (halves within a kb-block), keyed on lr&7
    const int kidx0 = lr * 64 + ((lg ^ (lr & 7)) * 8);
    const int kidx1 = lr * 64 + (((4 + lg) ^ (lr & 7)) * 8);

    const int vk2 = tid & 31, vdq = tid >> 5;

    float m[2]    = {-1e30f, -1e30f};
    float lsum[2] = {0.f, 0.f};
    f32x4 xacc[2][4] = {};

    half4v va0, va1, vb0, vb1;
    {   // prologue: stage tile 0
        const half_t* kbase = K + hoff;
        glds16(kbase + koffH[0], &KsL[0][(w * 2 + 0) * 512]);
        glds16(kbase + koffH[1], &KsL[0][(w * 2 + 1) * 512]);
        const half_t* vsrc = V + hoff + (size_t)(2 * vk2) * DD + vdq * 8;
        va0 = *reinterpret_cast<const half4v*>(vsrc);
        va1 = *reinterpret_cast<const half4v*>(vsrc + 4);
        vb0 = *reinterpret_cast<const half4v*>(vsrc + DD);
        vb1 = *reinterpret_cast<const half4v*>(vsrc + DD + 4);
        #pragma unroll
        for (int i = 0; i < 4; ++i) {
            half2v p0 = {va0[i], vb0[i]};
            half2v p1 = {va1[i], vb1[i]};
            *reinterpret_cast<half2v*>(&Vt[0][(vdq * 8 + i) * 72 + 2 * vk2])     = p0;
            *reinterpret_cast<half2v*>(&Vt[0][(vdq * 8 + i + 4) * 72 + 2 * vk2]) = p1;
        }
    }
    __syncthreads();

    for (int t = 0; t < SS / 64; ++t) {
        const int cur = t & 1, nxt = cur ^ 1;
        if (t < SS / 64 - 1) {   // issue next-tile loads early (T14)
            const half_t* kbase = K + hoff + (size_t)(t + 1) * 64 * DD;
            glds16(kbase + koffH[0], &KsL[nxt][(w * 2 + 0) * 512]);
            glds16(kbase + koffH[1], &KsL[nxt][(w * 2 + 1) * 512]);
            const half_t* vsrc = V + hoff + (size_t)((t + 1) * 64 + 2 * vk2) * DD + vdq * 8;
            va0 = *reinterpret_cast<const half4v*>(vsrc);
            va1 = *reinterpret_cast<const half4v*>(vsrc + 4);
            vb0 = *reinterpret_cast<const half4v*>(vsrc + DD);
            vb1 = *reinterpret_cast<const half4v*>(vsrc + DD + 4);
        }

        half8v kf[4][2];
        #pragma unroll
        for (int kb = 0; kb < 4; ++kb) {
            kf[kb][0] = *reinterpret_cast<const half8v*>(&KsL[cur][kb * 1024 + kidx0]);
            kf[kb][1] = *reinterpret_cast<const half8v*>(&KsL[cur][kb * 1024 + kidx1]);
        }

        half8v af2[2][2];   // PV B-fragments: [qset][k-window of 32]
        #pragma unroll
        for (int s = 0; s < 2; ++s) {
            f32x4 c[4] = {};
            __builtin_amdgcn_s_setprio(1);
            #pragma unroll
            for (int kb = 0; kb < 4; ++kb)
                #pragma unroll
                for (int hb = 0; hb < 2; ++hb)
                    c[kb] = __builtin_amdgcn_mfma_f32_16x16x32_f16(kf[kb][hb], qf[s][hb], c[kb], 0, 0, 0);
            __builtin_amdgcn_s_setprio(0);

            // f32 max tree (permutation-invariant)
            float r0 = fmaxf(fmaxf(c[0][0], c[0][1]), fmaxf(c[0][2], c[0][3]));
            float r1 = fmaxf(fmaxf(c[1][0], c[1][1]), fmaxf(c[1][2], c[1][3]));
            float r2 = fmaxf(fmaxf(c[2][0], c[2][1]), fmaxf(c[2][2], c[2][3]));
            float r3 = fmaxf(fmaxf(c[3][0], c[3][1]), fmaxf(c[3][2], c[3][3]));
            float rmax = fmaxf(fmaxf(r0, r1), fmaxf(r2, r3));
            rmax = fmaxf(rmax, __shfl_xor(rmax, 16, 64));
            rmax = fmaxf(rmax, __shfl_xor(rmax, 32, 64));

            if (__any(rmax > m[s] + 8.0f)) {   // defer-max fold
                const float mn = fmaxf(m[s], rmax);
                const float sc = __expf(m[s] - mn);
                lsum[s] *= sc;
                #pragma unroll
                for (int db = 0; db < 4; ++db)
                    #pragma unroll
                    for (int j = 0; j < 4; ++j)
                        xacc[s][db][j] *= sc;
                m[s] = mn;
            }

            const float L2E = 1.4426950408889634f;
            const float nm2 = m[s] * -L2E;
            float ps = 0.f;
            #pragma unroll
            for (int kb = 0; kb < 4; ++kb) {
#ifdef ATTN_EXP2
                const float p0 = ATTN_EXP2(__builtin_fmaf(c[kb][0], L2E, nm2));
                const float p1 = ATTN_EXP2(__builtin_fmaf(c[kb][1], L2E, nm2));
                const float p2 = ATTN_EXP2(__builtin_fmaf(c[kb][2], L2E, nm2));
                const float p3 = ATTN_EXP2(__builtin_fmaf(c[kb][3], L2E, nm2));
#else
                const float p0 = __expf(c[kb][0] - m[s]);
                const float p1 = __expf(c[kb][1] - m[s]);
                const float p2 = __expf(c[kb][2] - m[s]);
                const float p3 = __expf(c[kb][3] - m[s]);
#endif
                ps += (p0 + p1) + (p2 + p3);
                // c[kb][j] = key pi(kb*16+4lg+j) = 32*(kb>>1) + 8*lg + 4*(kb&1) + j
#ifdef ATTN_PKRTZ
                auto lo = __builtin_amdgcn_cvt_pkrtz(p0, p1);   // __fp16 x2
                auto hi = __builtin_amdgcn_cvt_pkrtz(p2, p3);
                af2[s][kb >> 1][(kb & 1) * 4 + 0] = (half_t)lo[0];
                af2[s][kb >> 1][(kb & 1) * 4 + 1] = (half_t)lo[1];
                af2[s][kb >> 1][(kb & 1) * 4 + 2] = (half_t)hi[0];
                af2[s][kb >> 1][(kb & 1) * 4 + 3] = (half_t)hi[1];
#else
                af2[s][kb >> 1][(kb & 1) * 4 + 0] = (half_t)p0;
                af2[s][kb >> 1][(kb & 1) * 4 + 1] = (half_t)p1;
                af2[s][kb >> 1][(kb & 1) * 4 + 2] = (half_t)p2;
                af2[s][kb >> 1][(kb & 1) * 4 + 3] = (half_t)p3;
#endif
            }
            ps += __shfl_xor(ps, 16, 64);
            ps += __shfl_xor(ps, 32, 64);
            lsum[s] += ps;
        }

        // PV: full-rate x32 MFMA, 8 b128 Vt reads (conflict-free)
        __builtin_amdgcn_s_setprio(1);
        #pragma unroll
        for (int db = 0; db < 4; ++db)
            #pragma unroll
            for (int kb2 = 0; kb2 < 2; ++kb2) {
                half8v vf = *reinterpret_cast<const half8v*>(
                    &Vt[cur][(db * 16 + lr) * 72 + kb2 * 32 + 8 * lg]);
                xacc[0][db] = __builtin_amdgcn_mfma_f32_16x16x32_f16(vf, af2[0][kb2], xacc[0][db], 0, 0, 0);
                xacc[1][db] = __builtin_amdgcn_mfma_f32_16x16x32_f16(vf, af2[1][kb2], xacc[1][db], 0, 0, 0);
            }
        __builtin_amdgcn_s_setprio(0);

        if (t < SS / 64 - 1) {   // write V-transpose into other buffer
            #pragma unroll
            for (int i = 0; i < 4; ++i) {
                half2v p0 = {va0[i], vb0[i]};
                half2v p1 = {va1[i], vb1[i]};
                *reinterpret_cast<half2v*>(&Vt[nxt][(vdq * 8 + i) * 72 + 2 * vk2])     = p0;
                *reinterpret_cast<half2v*>(&Vt[nxt][(vdq * 8 + i + 4) * 72 + 2 * vk2]) = p1;
            }
        }
        __syncthreads();
    }

    #pragma unroll
    for (int s = 0; s < 2; ++s) {
        const float invl = 1.0f / lsum[s];
        half_t* xp = X + hoff + (size_t)(q0 + s * 16 + lr) * DD;
        #pragma unroll
        for (int db = 0; db < 4; ++db) {
            half4v o;
            #pragma unroll
            for (int j = 0; j < 4; ++j) o[j] = (half_t)(xacc[s][db][j] * invl);
            *reinterpret_cast<half4v*>(xp + db * 16 + 4 * lg) = o;
        }
    }
}

extern "C" void kernel_launch(void* const* d_in, const int* in_sizes, int n_in,
                              void* d_out, int out_size, void* d_ws, size_t ws_size,
                              hipStream_t stream) {
    const float* q   = (const float*)d_in[0];
    const float* k   = (const float*)d_in[1];
    const float* v   = (const float*)d_in[2];
    const float* Wq  = (const float*)d_in[3];
    const float* bq  = (const float*)d_in[4];
    const float* Wk  = (const float*)d_in[5];
    const float* bk  = (const float*)d_in[6];
    const float* Wv  = (const float*)d_in[7];
    const float* bv  = (const float*)d_in[8];
    const float* Wo  = (const float*)d_in[9];
    const float* bo  = (const float*)d_in[10];
    float* out = (float*)d_out;

    const size_t MB = 1ull << 20;
    const size_t ACT = (size_t)MTOT * DD;   // 8.39M elems
    const size_t WEL = (size_t)DD * DD;     // 1.05M elems

    half_t* q16 = (half_t*)d_ws;
    half_t* k16 = q16 + ACT;
    half_t* v16 = k16 + ACT;
    half_t* x16 = v16 + ACT;

    dim3 gblk(256);
    dim3 ablk(256);
    dim3 agrd(1024);

    // main path: ws holds q16..x16 (67.1MB) + wh (8.4MB) = 75.5 MB.
    // A-cast scratch lives in d_out (exactly 2*ACT halves; overwritten by
    // gemm_out at the end) + the x16 slot (dead until attn writes it).
    if (ws_size >= 76 * MB) {
        half_t* wh = x16 + ACT;               // 4 * WEL (f16 casts of Wq..Wo)
        half_t* qa = (half_t*)d_out;          // ACT halves (scratch in d_out)
        half_t* ka = qa + ACT;                // ACT halves (scratch in d_out)
        half_t* va = x16;                     // ACT halves (x16 slot, dead until attn)

        dim3 wsgrd(WEL / 4 / 256, 1, 4);
        hipLaunchKernelGGL(cast_w4, wsgrd, gblk, 0, stream,
                           Wq, Wk, Wv, Wo, wh);

        dim3 asgrd(ACT / 4 / 256, 1, 3);
        hipLaunchKernelGGL(cast_a3, asgrd, gblk, 0, stream,
                           q, k, v, qa, ka, va);

        dim3 pgrd(MTOT / 128, DD / 128, 3);   // (m=64, n=8, z=3)
        hipLaunchKernelGGL(gemm_projf, pgrd, gblk, 0, stream,
                           qa, ka, va, wh, bq, bk, bv, q16, k16, v16);

        hipLaunchKernelGGL(attn_fused, agrd, ablk, 0, stream, q16, k16, v16, x16);

        dim3 ogrd(MTOT / 128, DD / 128);      // (m=64, n=8)
        hipLaunchKernelGGL(gemm_out, ogrd, gblk, 0, stream,
                           x16, wh + 3 * WEL, bo, out);
    } else if (ws_size >= 72 * MB) {
        half_t* wh = x16 + ACT;
        half_t* wl = wh + WEL;
        const int nw4 = (int)(WEL / 4);
        dim3 sgW((nw4 + 255) / 256);
        dim3 ggrd(DD / 128, MTOT / 128);

        hipLaunchKernelGGL(split_hi_lo, sgW, gblk, 0, stream, Wq, wh, wl, nw4);
        hipLaunchKernelGGL((gemm3s<1, half_t>), ggrd, gblk, 0, stream,
                           nullptr, nullptr, q, wh, wl, bq, q16, DD, DD);
        hipLaunchKernelGGL(split_hi_lo, sgW, gblk, 0, stream, Wk, wh, wl, nw4);
        hipLaunchKernelGGL((gemm3s<1, half_t>), ggrd, gblk, 0, stream,
                           nullptr, nullptr, k, wh, wl, bk, k16, DD, DD);
        hipLaunchKernelGGL(split_hi_lo, sgW, gblk, 0, stream, Wv, wh, wl, nw4);
        hipLaunchKernelGGL((gemm3s<1, half_t>), ggrd, gblk, 0, stream,
                           nullptr, nullptr, v, wh, wl, bv, v16, DD, DD);

        hipLaunchKernelGGL(attn_fused, agrd, ablk, 0, stream, q16, k16, v16, x16);

        hipLaunchKernelGGL(split_hi_lo, sgW, gblk, 0, stream, Wo, wh, wl, nw4);
        hipLaunchKernelGGL((gemm3s<2, float>), ggrd, gblk, 0, stream,
                           x16, nullptr, nullptr, wh, wl, bo, out, DD, DD);
    } else {
        dim3 blk(16, 16);
        dim3 grd(DD / 64, MTOT / 64);
        hipLaunchKernelGGL((gemm_bias<float, half_t>), grd, blk, 0, stream,
                           q, Wq, bq, q16, MTOT, DD, DD);
        hipLaunchKernelGGL((gemm_bias<float, half_t>), grd, blk, 0, stream,
                           k, Wk, bk, k16, MTOT, DD, DD);
        hipLaunchKernelGGL((gemm_bias<float, half_t>), grd, blk, 0, stream,
                           v, Wv, bv, v16, MTOT, DD, DD);
        hipLaunchKernelGGL(attn_fused, agrd, ablk, 0, stream, q16, k16, v16, x16);
        hipLaunchKernelGGL((gemm_bias<half_t, float>), grd, blk, 0, stream,
                           x16, Wo, bo, out, MTOT, DD, DD);
    }
}

// Round 18
// 210.564 us; speedup vs baseline: 1.1717x; 1.1717x over previous
//
#include <hip/hip_runtime.h>
#include <cstdint>

#define BB 4
#define SS 2048
#define DD 1024
#define HH 16
#define HDIM 64
#define MTOT (BB*SS)

using half_t = _Float16;
typedef _Float16 half2v __attribute__((ext_vector_type(2)));
typedef _Float16 half4v __attribute__((ext_vector_type(4)));
typedef _Float16 half8v __attribute__((ext_vector_type(8)));
typedef float f32x4 __attribute__((ext_vector_type(4)));

#if defined(__has_builtin)
#if __has_builtin(__builtin_amdgcn_exp2f)
#define ATTN_EXP2(x) __builtin_amdgcn_exp2f(x)
#endif
#if __has_builtin(__builtin_amdgcn_cvt_pkrtz)
#define ATTN_PKRTZ 1
#endif
#endif

// async global->LDS, 16B per lane; LDS dest = wave-uniform base + lane*16
__device__ __forceinline__ void glds16(const half_t* g, half_t* l) {
    __builtin_amdgcn_global_load_lds(g, l, 16, 0, 0);
}

// ---------------- fp32 -> (hi,lo) f16 split (fallback path) ----------------
__global__ __launch_bounds__(256) void split_hi_lo(const float* __restrict__ x,
    half_t* __restrict__ hi, half_t* __restrict__ lo, int n4)
{
    const int i = blockIdx.x * blockDim.x + threadIdx.x;
    if (i >= n4) return;
    float4 v = reinterpret_cast<const float4*>(x)[i];
    float vv[4] = {v.x, v.y, v.z, v.w};
    half4v h, l;
    #pragma unroll
    for (int j = 0; j < 4; ++j) {
        half_t hh = (half_t)vv[j];
        h[j] = hh;
        l[j] = (half_t)(vv[j] - (float)hh);
    }
    reinterpret_cast<half4v*>(hi)[i] = h;
    reinterpret_cast<half4v*>(lo)[i] = l;
}

// ---------------- cast 4 weight matrices to f16 (hi only) in one launch ----------------
__global__ __launch_bounds__(256) void cast_w4(
    const float* __restrict__ w0, const float* __restrict__ w1,
    const float* __restrict__ w2, const float* __restrict__ w3,
    half_t* __restrict__ hi)
{
    const int z = blockIdx.z;
    const float* src = z == 0 ? w0 : z == 1 ? w1 : z == 2 ? w2 : w3;
    const size_t base4 = (size_t)z * (DD * DD / 4);
    const size_t i = base4 + blockIdx.x * 256 + threadIdx.x;
    float4 v = reinterpret_cast<const float4*>(src)[blockIdx.x * 256 + threadIdx.x];
    float vv[4] = {v.x, v.y, v.z, v.w};
    half4v h;
    #pragma unroll
    for (int j = 0; j < 4; ++j) h[j] = (half_t)vv[j];
    reinterpret_cast<half4v*>(hi)[i] = h;
}

// ---------------- projection GEMM: C[z] = f16(A[z] @ f16(W[z])^T + b[z]) ----------------
// Single-product f16 MFMA. 2-deep pipeline, round-8 measured-best order.
__global__ __launch_bounds__(256, 4) void gemm_proj(
    const float* __restrict__ A0, const float* __restrict__ A1,
    const float* __restrict__ A2,
    const half_t* __restrict__ WH,
    const float* __restrict__ B0, const float* __restrict__ B1,
    const float* __restrict__ B2,
    half_t* __restrict__ C0, half_t* __restrict__ C1, half_t* __restrict__ C2)
{
    __shared__ __align__(16) half_t AhS[2][128 * 32];
    __shared__ __align__(16) half_t WhS[2][128 * 32];

    const int z = blockIdx.z;
    const float*  A    = z == 0 ? A0 : z == 1 ? A1 : A2;
    const float*  bias = z == 0 ? B0 : z == 1 ? B1 : B2;
    half_t*       C    = z == 0 ? C0 : z == 1 ? C1 : C2;
    const half_t* WHz  = WH + (size_t)z * (DD * DD);

    const int tid = threadIdx.x;
    const int l = tid & 63, w = tid >> 6;
    const int lr = l & 15, lg = l >> 4;
    const int wr = w >> 1, wc = w & 1;
    const int m0 = blockIdx.x * 128, n0 = blockIdx.y * 128;

    const int arow = tid >> 2;          // 0..63 (rows j*64+arow)
    const int acol = (tid & 3) * 8;     // 0,8,16,24
    const int wlrow = l >> 2, wlcol = (l & 3) * 8;

    f32x4 acc[4][4] = {};
    float4 av[2][2];

    // --- prologue: stage tile 0, prefetch A(tile 1) regs ---
    #pragma unroll
    for (int j = 0; j < 2; ++j) {
        const float* ap = A + (size_t)(m0 + j * 64 + arow) * DD + acol;
        av[j][0] = *reinterpret_cast<const float4*>(ap);
        av[j][1] = *reinterpret_cast<const float4*>(ap + 4);
    }
    #pragma unroll
    for (int j = 0; j < 2; ++j) {
        half_t hb[8];
        float v0[4] = {av[j][0].x, av[j][0].y, av[j][0].z, av[j][0].w};
        float v1[4] = {av[j][1].x, av[j][1].y, av[j][1].z, av[j][1].w};
        #pragma unroll
        for (int e = 0; e < 4; ++e) { hb[e] = (half_t)v0[e]; hb[4 + e] = (half_t)v1[e]; }
        *reinterpret_cast<int4*>(&AhS[0][(j * 64 + arow) * 32 + acol]) = *reinterpret_cast<int4*>(hb);
    }
    #pragma unroll
    for (int i = 0; i < 2; ++i) {
        const int rr = (w * 2 + i) * 16 + wlrow;
        glds16(WHz + (size_t)(n0 + rr) * DD + wlcol, &WhS[0][(w * 2 + i) * 512]);
    }
    #pragma unroll
    for (int j = 0; j < 2; ++j) {
        const float* ap = A + (size_t)(m0 + j * 64 + arow) * DD + 32 + acol;
        av[j][0] = *reinterpret_cast<const float4*>(ap);
        av[j][1] = *reinterpret_cast<const float4*>(ap + 4);
    }
    __syncthreads();

    for (int t = 0; t < 32; ++t) {
        const int cur = t & 1, nxt = cur ^ 1;
        if (t < 31) {
            // issue next-tile W loads FIRST (async, hide under MFMAs)
            const int kk1 = (t + 1) * 32;
            #pragma unroll
            for (int i = 0; i < 2; ++i) {
                const int rr = (w * 2 + i) * 16 + wlrow;
                glds16(WHz + (size_t)(n0 + rr) * DD + kk1 + wlcol, &WhS[nxt][(w * 2 + i) * 512]);
            }
            // hi-cast prefetched A(t+1) -> LDS
            #pragma unroll
            for (int j = 0; j < 2; ++j) {
                half_t hb[8];
                float v0[4] = {av[j][0].x, av[j][0].y, av[j][0].z, av[j][0].w};
                float v1[4] = {av[j][1].x, av[j][1].y, av[j][1].z, av[j][1].w};
                #pragma unroll
                for (int e = 0; e < 4; ++e) { hb[e] = (half_t)v0[e]; hb[4 + e] = (half_t)v1[e]; }
                *reinterpret_cast<int4*>(&AhS[nxt][(j * 64 + arow) * 32 + acol]) = *reinterpret_cast<int4*>(hb);
            }
        }

        half8v af[4];
        #pragma unroll
        for (int mt = 0; mt < 4; ++mt)
            af[mt] = *reinterpret_cast<const half8v*>(&AhS[cur][(wr * 64 + mt * 16 + lr) * 32 + 8 * lg]);
        #pragma unroll
        for (int nt = 0; nt < 4; ++nt) {
            half8v wf = *reinterpret_cast<const half8v*>(&WhS[cur][(wc * 64 + nt * 16 + lr) * 32 + 8 * lg]);
            #pragma unroll
            for (int mt = 0; mt < 4; ++mt)
                acc[mt][nt] = __builtin_amdgcn_mfma_f32_16x16x32_f16(af[mt], wf, acc[mt][nt], 0, 0, 0);
        }

        if (t < 30) {   // prefetch A(t+2) regs (round-8 measured-best placement)
            const int kk2 = (t + 2) * 32;
            #pragma unroll
            for (int j = 0; j < 2; ++j) {
                const float* ap = A + (size_t)(m0 + j * 64 + arow) * DD + kk2 + acol;
                av[j][0] = *reinterpret_cast<const float4*>(ap);
                av[j][1] = *reinterpret_cast<const float4*>(ap + 4);
            }
        }
        __syncthreads();   // one drain per tile
    }

    #pragma unroll
    for (int nt = 0; nt < 4; ++nt) {
        const int n = n0 + wc * 64 + nt * 16 + lr;
        const float bn = bias[n];
        #pragma unroll
        for (int mt = 0; mt < 4; ++mt) {
            const int mbase = m0 + wr * 64 + mt * 16 + 4 * lg;
            #pragma unroll
            for (int j = 0; j < 4; ++j)
                C[(size_t)(mbase + j) * DD + n] = (half_t)(acc[mt][nt][j] + bn);
        }
    }
}

// ---------------- output GEMM: out = x16 @ f16(Wo)^T + bo ----------------
__global__ __launch_bounds__(256, 4) void gemm_out(
    const half_t* __restrict__ Ag,
    const half_t* __restrict__ WHz,
    const float* __restrict__ bias, float* __restrict__ C)
{
    __shared__ __align__(16) half_t AhS[2][128 * 32];
    __shared__ __align__(16) half_t WhS[2][128 * 32];

    const int tid = threadIdx.x;
    const int l = tid & 63, w = tid >> 6;
    const int lr = l & 15, lg = l >> 4;
    const int wr = w >> 1, wc = w & 1;
    const int m0 = blockIdx.x * 128, n0 = blockIdx.y * 128;
    const int wlrow = l >> 2, wlcol = (l & 3) * 8;

    f32x4 acc[4][4] = {};

    // prologue: stage tile 0
    #pragma unroll
    for (int i = 0; i < 2; ++i) {
        const int rr = (w * 2 + i) * 16 + wlrow;
        glds16(Ag  + (size_t)(m0 + rr) * DD + wlcol, &AhS[0][(w * 2 + i) * 512]);
        glds16(WHz + (size_t)(n0 + rr) * DD + wlcol, &WhS[0][(w * 2 + i) * 512]);
    }
    __syncthreads();

    for (int t = 0; t < 32; ++t) {
        const int cur = t & 1, nxt = cur ^ 1;
        if (t < 31) {
            const int kk1 = (t + 1) * 32;
            #pragma unroll
            for (int i = 0; i < 2; ++i) {
                const int rr = (w * 2 + i) * 16 + wlrow;
                glds16(Ag  + (size_t)(m0 + rr) * DD + kk1 + wlcol, &AhS[nxt][(w * 2 + i) * 512]);
                glds16(WHz + (size_t)(n0 + rr) * DD + kk1 + wlcol, &WhS[nxt][(w * 2 + i) * 512]);
            }
        }

        half8v af[4];
        #pragma unroll
        for (int mt = 0; mt < 4; ++mt)
            af[mt] = *reinterpret_cast<const half8v*>(&AhS[cur][(wr * 64 + mt * 16 + lr) * 32 + 8 * lg]);
        #pragma unroll
        for (int nt = 0; nt < 4; ++nt) {
            half8v wf = *reinterpret_cast<const half8v*>(&WhS[cur][(wc * 64 + nt * 16 + lr) * 32 + 8 * lg]);
            #pragma unroll
            for (int mt = 0; mt < 4; ++mt)
                acc[mt][nt] = __builtin_amdgcn_mfma_f32_16x16x32_f16(af[mt], wf, acc[mt][nt], 0, 0, 0);
        }
        __syncthreads();
    }

    #pragma unroll
    for (int nt = 0; nt < 4; ++nt) {
        const int n = n0 + wc * 64 + nt * 16 + lr;
        const float bn = bias[n];
        #pragma unroll
        for (int mt = 0; mt < 4; ++mt) {
            const int mbase = m0 + wr * 64 + mt * 16 + 4 * lg;
            #pragma unroll
            for (int j = 0; j < 4; ++j)
                C[(size_t)(mbase + j) * DD + n] = acc[mt][nt][j] + bn;
        }
    }
}

// ---------------- old split GEMM (fallback path only) ----------------
template<int MODE, typename TC>
__global__ __launch_bounds__(256) void gemm3s(
    const half_t* __restrict__ Ah, const half_t* __restrict__ Al,
    const float* __restrict__ Af,
    const half_t* __restrict__ Wh, const half_t* __restrict__ Wl,
    const float* __restrict__ bias, TC* __restrict__ C,
    int Kdim, int Ndim)
{
    constexpr int LDT = 72;
    __shared__ __align__(16) half_t As[128 * LDT];
    __shared__ __align__(16) half_t Ws[128 * LDT];
    const int tid = threadIdx.x;
    const int l = tid & 63, w = tid >> 6;
    const int lr = l & 15, lg = l >> 4;
    const int wr = w >> 1, wc = w & 1;
    const int m0 = blockIdx.y * 128, n0 = blockIdx.x * 128;
    const int r = tid >> 1, t = tid & 1;

    f32x4 acc[4][4] = {};

    for (int kk = 0; kk < Kdim; kk += 32) {
        __syncthreads();
        if constexpr (MODE == 1) {
            const float* ap = Af + (size_t)(m0 + r) * Kdim + kk + 16 * t;
            half_t hbuf[16], lbuf[16];
            #pragma unroll
            for (int u = 0; u < 4; ++u) {
                float4 v = *reinterpret_cast<const float4*>(ap + 4 * u);
                float vv[4] = {v.x, v.y, v.z, v.w};
                #pragma unroll
                for (int j = 0; j < 4; ++j) {
                    half_t hh = (half_t)vv[j];
                    hbuf[4 * u + j] = hh;
                    lbuf[4 * u + j] = (half_t)(vv[j] - (float)hh);
                }
            }
            *reinterpret_cast<int4*>(&As[r * LDT + 16 * t])          = *reinterpret_cast<int4*>(hbuf);
            *reinterpret_cast<int4*>(&As[r * LDT + 16 * t + 8])      = *reinterpret_cast<int4*>(hbuf + 8);
            *reinterpret_cast<int4*>(&As[r * LDT + 40 + 16 * t])     = *reinterpret_cast<int4*>(lbuf);
            *reinterpret_cast<int4*>(&As[r * LDT + 40 + 16 * t + 8]) = *reinterpret_cast<int4*>(lbuf + 8);
        } else {
            const half_t* ap = Ah + (size_t)(m0 + r) * Kdim + kk + 16 * t;
            *reinterpret_cast<int4*>(&As[r * LDT + 16 * t])     = *reinterpret_cast<const int4*>(ap);
            *reinterpret_cast<int4*>(&As[r * LDT + 16 * t + 8]) = *reinterpret_cast<const int4*>(ap + 8);
        }
        {
            const half_t* wp = Wh + (size_t)(n0 + r) * Kdim + kk + 16 * t;
            *reinterpret_cast<int4*>(&Ws[r * LDT + 16 * t])     = *reinterpret_cast<const int4*>(wp);
            *reinterpret_cast<int4*>(&Ws[r * LDT + 16 * t + 8]) = *reinterpret_cast<const int4*>(wp + 8);
            const half_t* wlp = Wl + (size_t)(n0 + r) * Kdim + kk + 16 * t;
            *reinterpret_cast<int4*>(&Ws[r * LDT + 40 + 16 * t])     = *reinterpret_cast<const int4*>(wlp);
            *reinterpret_cast<int4*>(&Ws[r * LDT + 40 + 16 * t + 8]) = *reinterpret_cast<const int4*>(wlp + 8);
        }
        __syncthreads();

        half8v af[4], alf[4];
        #pragma unroll
        for (int mt = 0; mt < 4; ++mt) {
            af[mt] = *reinterpret_cast<const half8v*>(&As[(wr * 64 + mt * 16 + lr) * LDT + 8 * lg]);
            if constexpr (MODE != 2)
                alf[mt] = *reinterpret_cast<const half8v*>(&As[(wr * 64 + mt * 16 + lr) * LDT + 40 + 8 * lg]);
        }
        #pragma unroll
        for (int nt = 0; nt < 4; ++nt) {
            half8v wf  = *reinterpret_cast<const half8v*>(&Ws[(wc * 64 + nt * 16 + lr) * LDT + 8 * lg]);
            half8v wlf = *reinterpret_cast<const half8v*>(&Ws[(wc * 64 + nt * 16 + lr) * LDT + 40 + 8 * lg]);
            #pragma unroll
            for (int mt = 0; mt < 4; ++mt) {
                acc[mt][nt] = __builtin_amdgcn_mfma_f32_16x16x32_f16(af[mt], wf, acc[mt][nt], 0, 0, 0);
                acc[mt][nt] = __builtin_amdgcn_mfma_f32_16x16x32_f16(af[mt], wlf, acc[mt][nt], 0, 0, 0);
                if constexpr (MODE != 2)
                    acc[mt][nt] = __builtin_amdgcn_mfma_f32_16x16x32_f16(alf[mt], wf, acc[mt][nt], 0, 0, 0);
            }
        }
    }

    #pragma unroll
    for (int nt = 0; nt < 4; ++nt) {
        const int n = n0 + wc * 64 + nt * 16 + lr;
        const float bn = bias[n];
        #pragma unroll
        for (int mt = 0; mt < 4; ++mt) {
            const int mbase = m0 + wr * 64 + mt * 16 + 4 * lg;
            #pragma unroll
            for (int j = 0; j < 4; ++j) {
                float v = acc[mt][nt][j] + bn;
                if constexpr (sizeof(TC) == 4)
                    C[(size_t)(mbase + j) * Ndim + n] = v;
                else
                    C[(size_t)(mbase + j) * Ndim + n] = (half_t)v;
            }
        }
    }
}

// ---------------- fp32 vector GEMM (ultimate fallback only) ----------------
template<typename TA, typename TC>
__global__ __launch_bounds__(256) void gemm_bias(const TA* __restrict__ A,
    const float* __restrict__ W, const float* __restrict__ bias,
    TC* __restrict__ C, int Mdim, int Ndim, int Kdim)
{
    constexpr int BK = 16;
    __shared__ float As[BK][68];
    __shared__ float Ws[BK][68];
    const int tx = threadIdx.x, ty = threadIdx.y;
    const int tid = ty * 16 + tx;
    const int m0 = blockIdx.y * 64, n0 = blockIdx.x * 64;
    const int lrow = tid >> 2;
    const int lc4  = (tid & 3) * 4;

    float acc[4][4] = {};
    for (int kk = 0; kk < Kdim; kk += BK) {
        {
            const TA* ap = A + (size_t)(m0 + lrow) * Kdim + kk + lc4;
            float a0, a1, a2, a3;
            if constexpr (sizeof(TA) == 4) {
                float4 v = *reinterpret_cast<const float4*>(ap);
                a0 = v.x; a1 = v.y; a2 = v.z; a3 = v.w;
            } else {
                half2v v0 = *reinterpret_cast<const half2v*>(ap);
                half2v v1 = *reinterpret_cast<const half2v*>(ap + 2);
                a0 = (float)v0[0]; a1 = (float)v0[1];
                a2 = (float)v1[0]; a3 = (float)v1[1];
            }
            As[lc4 + 0][lrow] = a0; As[lc4 + 1][lrow] = a1;
            As[lc4 + 2][lrow] = a2; As[lc4 + 3][lrow] = a3;
            const float* wp = W + (size_t)(n0 + lrow) * Kdim + kk + lc4;
            float4 wv = *reinterpret_cast<const float4*>(wp);
            Ws[lc4 + 0][lrow] = wv.x; Ws[lc4 + 1][lrow] = wv.y;
            Ws[lc4 + 2][lrow] = wv.z; Ws[lc4 + 3][lrow] = wv.w;
        }
        __syncthreads();
        #pragma unroll
        for (int k = 0; k < BK; ++k) {
            float4 av = *reinterpret_cast<const float4*>(&As[k][ty * 4]);
            float4 bv = *reinterpret_cast<const float4*>(&Ws[k][tx * 4]);
            float a[4] = {av.x, av.y, av.z, av.w};
            float b[4] = {bv.x, bv.y, bv.z, bv.w};
            #pragma unroll
            for (int i = 0; i < 4; ++i)
                #pragma unroll
                for (int j = 0; j < 4; ++j)
                    acc[i][j] = fmaf(a[i], b[j], acc[i][j]);
        }
        __syncthreads();
    }
    #pragma unroll
    for (int i = 0; i < 4; ++i) {
        const int m = m0 + ty * 4 + i;
        #pragma unroll
        for (int j = 0; j < 4; ++j) {
            const int n = n0 + tx * 4 + j;
            float v = acc[i][j] + bias[n];
            if constexpr (sizeof(TC) == 4)
                C[(size_t)m * Ndim + n] = v;
            else
                C[(size_t)m * Ndim + n] = (half_t)v;
        }
    }
}

// ---------------- single-pass fused attention ----------------
// PV on full-rate mfma_f32_16x16x32_f16 via a static K-row permutation in
// LDS: row R holds key pi(R) = 32*(R>>5&1) + 8*(R>>2&3) + 4*(R>>4&1) + (R&3)
// (bijective; applied by pre-permuting the per-lane GLOBAL source of
// global_load_lds, LDS stays linear). concat(af[2k2],af[2k2+1]) is exactly
// the x32 B-fragment for key window 32*k2 -> PV needs 16 MFMA/tile. V
// unchanged; Vt PV reads are 8 b128 loads, conflict-free. Max/sum are
// permutation-invariant. Softmax = round-13 best (f32 max + defer-max +
// exp2 + pkrtz).
__global__ __launch_bounds__(256, 4) void attn_fused(const half_t* __restrict__ Q,
    const half_t* __restrict__ K, const half_t* __restrict__ V,
    half_t* __restrict__ X)
{
    __shared__ __align__(16) half_t KsL[2][64 * 64];   // linear, swizzled+permuted content
    __shared__ __align__(16) half_t Vt[2][64 * 72];    // transposed V

    const int tid = threadIdx.x;
    const int l   = tid & 63;
    const int w   = tid >> 6;
    const int lr  = l & 15;
    const int lg  = l >> 4;

    const int phys = blockIdx.x;
    const int virt = (phys & 7) * 128 + (phys >> 3);
    const int qb = virt & 15;
    const int h  = (virt >> 4) & 15;
    const int b  = virt >> 8;

    const int q0 = qb * 128 + w * 32;
    const size_t hoff = (size_t)(b * SS) * DD + h * HDIM;

    // Q fragments, pre-scaled by 1/8
    half8v qf[2][2];
    #pragma unroll
    for (int s = 0; s < 2; ++s) {
        const half_t* qp = Q + hoff + (size_t)(q0 + s * 16 + lr) * DD;
        #pragma unroll
        for (int hb = 0; hb < 2; ++hb) {
            half8v v = *reinterpret_cast<const half8v*>(qp + hb * 32 + 8 * lg);
            #pragma unroll
            for (int e = 0; e < 8; ++e) v[e] *= (half_t)0.125f;
            qf[s][hb] = v;
        }
    }

    // K staging: per-lane global source offsets with row-permutation pi and
    // XOR chunk swizzle keyed on LDS row R (both-sides rule, m173 pattern)
    int koffH[2];
    #pragma unroll
    for (int i = 0; i < 2; ++i) {
        const int R    = (w * 2 + i) * 8 + (l >> 3);   // LDS row this lane fills
        const int gkey = ((R >> 5) & 1) * 32 + ((R >> 2) & 3) * 8
                       + ((R >> 4) & 1) * 4 + (R & 3); // pi(R)
        const int gc   = (l & 7) ^ (R & 7);
        koffH[i] = gkey * DD + gc * 8;
    }
    // swizzled frag-read indices (halves within a kb-block), keyed on lr&7
    const int kidx0 = lr * 64 + ((lg ^ (lr & 7)) * 8);
    const int kidx1 = lr * 64 + (((4 + lg) ^ (lr & 7)) * 8);

    const int vk2 = tid & 31, vdq = tid >> 5;

    float m[2]    = {-1e30f, -1e30f};
    float lsum[2] = {0.f, 0.f};
    f32x4 xacc[2][4] = {};

    half4v va0, va1, vb0, vb1;
    {   // prologue: stage tile 0
        const half_t* kbase = K + hoff;
        glds16(kbase + koffH[0], &KsL[0][(w * 2 + 0) * 512]);
        glds16(kbase + koffH[1], &KsL[0][(w * 2 + 1) * 512]);
        const half_t* vsrc = V + hoff + (size_t)(2 * vk2) * DD + vdq * 8;
        va0 = *reinterpret_cast<const half4v*>(vsrc);
        va1 = *reinterpret_cast<const half4v*>(vsrc + 4);
        vb0 = *reinterpret_cast<const half4v*>(vsrc + DD);
        vb1 = *reinterpret_cast<const half4v*>(vsrc + DD + 4);
        #pragma unroll
        for (int i = 0; i < 4; ++i) {
            half2v p0 = {va0[i], vb0[i]};
            half2v p1 = {va1[i], vb1[i]};
            *reinterpret_cast<half2v*>(&Vt[0][(vdq * 8 + i) * 72 + 2 * vk2])     = p0;
            *reinterpret_cast<half2v*>(&Vt[0][(vdq * 8 + i + 4) * 72 + 2 * vk2]) = p1;
        }
    }
    __syncthreads();

    for (int t = 0; t < SS / 64; ++t) {
        const int cur = t & 1, nxt = cur ^ 1;
        if (t < SS / 64 - 1) {   // issue next-tile loads early (T14)
            const half_t* kbase = K + hoff + (size_t)(t + 1) * 64 * DD;
            glds16(kbase + koffH[0], &KsL[nxt][(w * 2 + 0) * 512]);
            glds16(kbase + koffH[1], &KsL[nxt][(w * 2 + 1) * 512]);
            const half_t* vsrc = V + hoff + (size_t)((t + 1) * 64 + 2 * vk2) * DD + vdq * 8;
            va0 = *reinterpret_cast<const half4v*>(vsrc);
            va1 = *reinterpret_cast<const half4v*>(vsrc + 4);
            vb0 = *reinterpret_cast<const half4v*>(vsrc + DD);
            vb1 = *reinterpret_cast<const half4v*>(vsrc + DD + 4);
        }

        half8v kf[4][2];
        #pragma unroll
        for (int kb = 0; kb < 4; ++kb) {
            kf[kb][0] = *reinterpret_cast<const half8v*>(&KsL[cur][kb * 1024 + kidx0]);
            kf[kb][1] = *reinterpret_cast<const half8v*>(&KsL[cur][kb * 1024 + kidx1]);
        }

        half8v af2[2][2];   // PV B-fragments: [qset][k-window of 32]
        #pragma unroll
        for (int s = 0; s < 2; ++s) {
            f32x4 c[4] = {};
            __builtin_amdgcn_s_setprio(1);
            #pragma unroll
            for (int kb = 0; kb < 4; ++kb)
                #pragma unroll
                for (int hb = 0; hb < 2; ++hb)
                    c[kb] = __builtin_amdgcn_mfma_f32_16x16x32_f16(kf[kb][hb], qf[s][hb], c[kb], 0, 0, 0);
            __builtin_amdgcn_s_setprio(0);

            // f32 max tree (permutation-invariant)
            float r0 = fmaxf(fmaxf(c[0][0], c[0][1]), fmaxf(c[0][2], c[0][3]));
            float r1 = fmaxf(fmaxf(c[1][0], c[1][1]), fmaxf(c[1][2], c[1][3]));
            float r2 = fmaxf(fmaxf(c[2][0], c[2][1]), fmaxf(c[2][2], c[2][3]));
            float r3 = fmaxf(fmaxf(c[3][0], c[3][1]), fmaxf(c[3][2], c[3][3]));
            float rmax = fmaxf(fmaxf(r0, r1), fmaxf(r2, r3));
            rmax = fmaxf(rmax, __shfl_xor(rmax, 16, 64));
            rmax = fmaxf(rmax, __shfl_xor(rmax, 32, 64));

            if (__any(rmax > m[s] + 8.0f)) {   // defer-max fold
                const float mn = fmaxf(m[s], rmax);
                const float sc = __expf(m[s] - mn);
                lsum[s] *= sc;
                #pragma unroll
                for (int db = 0; db < 4; ++db)
                    #pragma unroll
                    for (int j = 0; j < 4; ++j)
                        xacc[s][db][j] *= sc;
                m[s] = mn;
            }

            const float L2E = 1.4426950408889634f;
            const float nm2 = m[s] * -L2E;
            float ps = 0.f;
            #pragma unroll
            for (int kb = 0; kb < 4; ++kb) {
#ifdef ATTN_EXP2
                const float p0 = ATTN_EXP2(__builtin_fmaf(c[kb][0], L2E, nm2));
                const float p1 = ATTN_EXP2(__builtin_fmaf(c[kb][1], L2E, nm2));
                const float p2 = ATTN_EXP2(__builtin_fmaf(c[kb][2], L2E, nm2));
                const float p3 = ATTN_EXP2(__builtin_fmaf(c[kb][3], L2E, nm2));
#else
                const float p0 = __expf(c[kb][0] - m[s]);
                const float p1 = __expf(c[kb][1] - m[s]);
                const float p2 = __expf(c[kb][2] - m[s]);
                const float p3 = __expf(c[kb][3] - m[s]);
#endif
                ps += (p0 + p1) + (p2 + p3);
                // c[kb][j] = key pi(kb*16+4lg+j) = 32*(kb>>1) + 8*lg + 4*(kb&1) + j
#ifdef ATTN_PKRTZ
                auto lo = __builtin_amdgcn_cvt_pkrtz(p0, p1);   // __fp16 x2
                auto hi = __builtin_amdgcn_cvt_pkrtz(p2, p3);
                af2[s][kb >> 1][(kb & 1) * 4 + 0] = (half_t)lo[0];
                af2[s][kb >> 1][(kb & 1) * 4 + 1] = (half_t)lo[1];
                af2[s][kb >> 1][(kb & 1) * 4 + 2] = (half_t)hi[0];
                af2[s][kb >> 1][(kb & 1) * 4 + 3] = (half_t)hi[1];
#else
                af2[s][kb >> 1][(kb & 1) * 4 + 0] = (half_t)p0;
                af2[s][kb >> 1][(kb & 1) * 4 + 1] = (half_t)p1;
                af2[s][kb >> 1][(kb & 1) * 4 + 2] = (half_t)p2;
                af2[s][kb >> 1][(kb & 1) * 4 + 3] = (half_t)p3;
#endif
            }
            ps += __shfl_xor(ps, 16, 64);
            ps += __shfl_xor(ps, 32, 64);
            lsum[s] += ps;
        }

        // PV: full-rate x32 MFMA, 8 b128 Vt reads (conflict-free)
        __builtin_amdgcn_s_setprio(1);
        #pragma unroll
        for (int db = 0; db < 4; ++db)
            #pragma unroll
            for (int kb2 = 0; kb2 < 2; ++kb2) {
                half8v vf = *reinterpret_cast<const half8v*>(
                    &Vt[cur][(db * 16 + lr) * 72 + kb2 * 32 + 8 * lg]);
                xacc[0][db] = __builtin_amdgcn_mfma_f32_16x16x32_f16(vf, af2[0][kb2], xacc[0][db], 0, 0, 0);
                xacc[1][db] = __builtin_amdgcn_mfma_f32_16x16x32_f16(vf, af2[1][kb2], xacc[1][db], 0, 0, 0);
            }
        __builtin_amdgcn_s_setprio(0);

        if (t < SS / 64 - 1) {   // write V-transpose into other buffer
            #pragma unroll
            for (int i = 0; i < 4; ++i) {
                half2v p0 = {va0[i], vb0[i]};
                half2v p1 = {va1[i], vb1[i]};
                *reinterpret_cast<half2v*>(&Vt[nxt][(vdq * 8 + i) * 72 + 2 * vk2])     = p0;
                *reinterpret_cast<half2v*>(&Vt[nxt][(vdq * 8 + i + 4) * 72 + 2 * vk2]) = p1;
            }
        }
        __syncthreads();
    }

    #pragma unroll
    for (int s = 0; s < 2; ++s) {
        const float invl = 1.0f / lsum[s];
        half_t* xp = X + hoff + (size_t)(q0 + s * 16 + lr) * DD;
        #pragma unroll
        for (int db = 0; db < 4; ++db) {
            half4v o;
            #pragma unroll
            for (int j = 0; j < 4; ++j) o[j] = (half_t)(xacc[s][db][j] * invl);
            *reinterpret_cast<half4v*>(xp + db * 16 + 4 * lg) = o;
        }
    }
}

extern "C" void kernel_launch(void* const* d_in, const int* in_sizes, int n_in,
                              void* d_out, int out_size, void* d_ws, size_t ws_size,
                              hipStream_t stream) {
    const float* q   = (const float*)d_in[0];
    const float* k   = (const float*)d_in[1];
    const float* v   = (const float*)d_in[2];
    const float* Wq  = (const float*)d_in[3];
    const float* bq  = (const float*)d_in[4];
    const float* Wk  = (const float*)d_in[5];
    const float* bk  = (const float*)d_in[6];
    const float* Wv  = (const float*)d_in[7];
    const float* bv  = (const float*)d_in[8];
    const float* Wo  = (const float*)d_in[9];
    const float* bo  = (const float*)d_in[10];
    float* out = (float*)d_out;

    const size_t MB = 1ull << 20;
    const size_t ACT = (size_t)MTOT * DD;   // 8.39M elems
    const size_t WEL = (size_t)DD * DD;     // 1.05M elems

    half_t* q16 = (half_t*)d_ws;
    half_t* k16 = q16 + ACT;
    half_t* v16 = k16 + ACT;
    half_t* x16 = v16 + ACT;

    dim3 gblk(256);
    dim3 ablk(256);
    dim3 agrd(1024);

    // main path: q16..x16 (4*ACT*2B = 67.1MB) + wh (4*WEL*2B = 8.4MB) = 75.5 MB
    if (ws_size >= 76 * MB) {
        half_t* wh = x16 + ACT;          // 4 * WEL (f16 casts of Wq,Wk,Wv,Wo)

        dim3 wsgrd(WEL / 4 / 256, 1, 4);
        hipLaunchKernelGGL(cast_w4, wsgrd, gblk, 0, stream,
                           Wq, Wk, Wv, Wo, wh);

        dim3 pgrd(MTOT / 128, DD / 128, 3);   // (m=64, n=8, z=3)
        hipLaunchKernelGGL(gemm_proj, pgrd, gblk, 0, stream,
                           q, k, v, wh, bq, bk, bv, q16, k16, v16);

        hipLaunchKernelGGL(attn_fused, agrd, ablk, 0, stream, q16, k16, v16, x16);

        dim3 ogrd(MTOT / 128, DD / 128);      // (m=64, n=8)
        hipLaunchKernelGGL(gemm_out, ogrd, gblk, 0, stream,
                           x16, wh + 3 * WEL, bo, out);
    } else if (ws_size >= 72 * MB) {
        half_t* wh = x16 + ACT;
        half_t* wl = wh + WEL;
        const int nw4 = (int)(WEL / 4);
        dim3 sgW((nw4 + 255) / 256);
        dim3 ggrd(DD / 128, MTOT / 128);

        hipLaunchKernelGGL(split_hi_lo, sgW, gblk, 0, stream, Wq, wh, wl, nw4);
        hipLaunchKernelGGL((gemm3s<1, half_t>), ggrd, gblk, 0, stream,
                           nullptr, nullptr, q, wh, wl, bq, q16, DD, DD);
        hipLaunchKernelGGL(split_hi_lo, sgW, gblk, 0, stream, Wk, wh, wl, nw4);
        hipLaunchKernelGGL((gemm3s<1, half_t>), ggrd, gblk, 0, stream,
                           nullptr, nullptr, k, wh, wl, bk, k16, DD, DD);
        hipLaunchKernelGGL(split_hi_lo, sgW, gblk, 0, stream, Wv, wh, wl, nw4);
        hipLaunchKernelGGL((gemm3s<1, half_t>), ggrd, gblk, 0, stream,
                           nullptr, nullptr, v, wh, wl, bv, v16, DD, DD);

        hipLaunchKernelGGL(attn_fused, agrd, ablk, 0, stream, q16, k16, v16, x16);

        hipLaunchKernelGGL(split_hi_lo, sgW, gblk, 0, stream, Wo, wh, wl, nw4);
        hipLaunchKernelGGL((gemm3s<2, float>), ggrd, gblk, 0, stream,
                           x16, nullptr, nullptr, wh, wl, bo, out, DD, DD);
    } else {
        dim3 blk(16, 16);
        dim3 grd(DD / 64, MTOT / 64);
        hipLaunchKernelGGL((gemm_bias<float, half_t>), grd, blk, 0, stream,
                           q, Wq, bq, q16, MTOT, DD, DD);
        hipLaunchKernelGGL((gemm_bias<float, half_t>), grd, blk, 0, stream,
                           k, Wk, bk, k16, MTOT, DD, DD);
        hipLaunchKernelGGL((gemm_bias<float, half_t>), grd, blk, 0, stream,
                           v, Wv, bv, v16, MTOT, DD, DD);
        hipLaunchKernelGGL(attn_fused, agrd, ablk, 0, stream, q16, k16, v16, x16);
        hipLaunchKernelGGL((gemm_bias<half_t, float>), grd, blk, 0, stream,
                           x16, Wo, bo, out, MTOT, DD, DD);
    }
}